// Round 1
// baseline (885.952 us; speedup 1.0000x reference)
//
#include <hip/hip_runtime.h>

#define NS 100000

typedef _Float16 half8v __attribute__((ext_vector_type(8)));
typedef _Float16 half4v __attribute__((ext_vector_type(4)));
typedef _Float16 half2v __attribute__((ext_vector_type(2)));
typedef float    f32x16 __attribute__((ext_vector_type(16)));
typedef unsigned int uint2v __attribute__((ext_vector_type(2)));

// ============================================================================
// Kernel 1: build Q per component (fp32, LDS), expm via scaling+squaring
// Taylor, then P(0.05)^{1,2,3,4}; store f16 row-major in d_ws:
//   Pw[m][v][64][64], v=0..3 -> P^(v+1), v=4 -> diag(pi)*P^1 (root fold)
// ============================================================================
__global__ __launch_bounds__(256) void prep_P(const float* __restrict__ rates,
                                              const float* __restrict__ pi_inv,
                                              _Float16* __restrict__ Pw) {
  __shared__ float Ab[4096];
  __shared__ float Tb[4096];
  __shared__ float Sb[4096];
  __shared__ float pi_l[64];
  __shared__ float red[64];
  __shared__ float sc_sh[2];
  const int t = threadIdx.x;
  const int m = blockIdx.x;

  // ---- pi from inverse stereographic projection ----
  if (t < 63) { float y = pi_inv[m * 63 + t]; red[t] = y * y; }
  __syncthreads();
  if (t == 0) { double ns = 0.0; for (int i = 0; i < 63; ++i) ns += red[i]; sc_sh[0] = (float)ns; }
  __syncthreads();
  {
    float ns = sc_sh[0];
    if (t < 64) {
      float ps;
      if (t < 63) { float y = pi_inv[m * 63 + t]; ps = 2.f * y / (ns + 1.f); }
      else        { ps = (ns - 1.f) / (ns + 1.f); }
      pi_l[t] = ps * ps;
    }
  }
  __syncthreads();

  // ---- Q (off-diag) in Ab ----
  for (int it = 0; it < 16; ++it) {
    int e = t + 256 * it, i = e >> 6, j = e & 63;
    float v = 0.f;
    if (i != j) {
      int ii = i < j ? i : j, jj = i < j ? j : i;
      int tri = ii * 63 - (ii * (ii - 1)) / 2 + (jj - ii - 1);
      float r = rates[m * 2016 + tri];
      v = r * r * pi_l[j];
    }
    Ab[e] = v;
  }
  __syncthreads();
  // ---- diagonal + emut ----
  if (t < 64) {
    float s = 0.f;
    for (int j = 0; j < 64; ++j) s += Ab[t * 64 + j];
    Ab[t * 64 + t] = -s;
    red[t] = pi_l[t] * s;
  }
  __syncthreads();
  if (t == 0) { double em = 0.0; for (int i = 0; i < 64; ++i) em += red[i]; sc_sh[0] = (float)(0.05 / em); }
  __syncthreads();
  const float sc0 = sc_sh[0];
  // ---- 1-norm of (0.05/emut)*Q -> scaling exponent ----
  if (t < 64) {
    float s = 0.f;
    for (int i = 0; i < 64; ++i) s += fabsf(Ab[i * 64 + t]);
    red[t] = s * fabsf(sc0);
  }
  __syncthreads();
  if (t == 0) {
    float n1 = 0.f; for (int i = 0; i < 64; ++i) n1 = fmaxf(n1, red[i]);
    int sq = 0;
    while (n1 > 0.3f && sq < 24) { n1 *= 0.5f; ++sq; }
    sc_sh[0] = ldexpf(sc0, -sq);
    sc_sh[1] = (float)sq;
  }
  __syncthreads();
  const float scl = sc_sh[0];
  const int   sq  = (int)sc_sh[1];
  // ---- A = scaled Q ; T = A ; S = I + A ----
  for (int it = 0; it < 16; ++it) {
    int e = t + 256 * it;
    float a = Ab[e] * scl;
    Ab[e] = a; Tb[e] = a;
    Sb[e] = a + (((e >> 6) == (e & 63)) ? 1.f : 0.f);
  }
  __syncthreads();

  const int ri = t >> 2, jb = (t & 3) * 16;
  // ---- Taylor series, 20 terms ----
  for (int k = 2; k <= 20; ++k) {
    float r[16];
#pragma unroll
    for (int j = 0; j < 16; ++j) r[j] = 0.f;
    for (int kk = 0; kk < 64; ++kk) {
      float a = Tb[ri * 64 + kk];
#pragma unroll
      for (int j = 0; j < 16; ++j) r[j] += a * Ab[kk * 64 + jb + j];
    }
    __syncthreads();
    float inv = 1.f / (float)k;
#pragma unroll
    for (int j = 0; j < 16; ++j) {
      float v = r[j] * inv;
      Tb[ri * 64 + jb + j] = v;
      Sb[ri * 64 + jb + j] += v;
    }
    __syncthreads();
  }
  // ---- repeated squaring ----
  for (int q = 0; q < sq; ++q) {
    float r[16];
#pragma unroll
    for (int j = 0; j < 16; ++j) r[j] = 0.f;
    for (int kk = 0; kk < 64; ++kk) {
      float a = Sb[ri * 64 + kk];
#pragma unroll
      for (int j = 0; j < 16; ++j) r[j] += a * Sb[kk * 64 + jb + j];
    }
    __syncthreads();
#pragma unroll
    for (int j = 0; j < 16; ++j) Sb[ri * 64 + jb + j] = r[j];
    __syncthreads();
  }

  _Float16* base = Pw + (size_t)m * 5 * 4096;
  // v0 = P1, v4 = diag(pi)*P1
  for (int it = 0; it < 16; ++it) {
    int e = t + 256 * it;
    float v = Sb[e];
    base[e]            = (_Float16)v;
    base[4 * 4096 + e] = (_Float16)(pi_l[e >> 6] * v);
  }
  // P2 = P1*P1 -> Ab
  {
    float r[16];
#pragma unroll
    for (int j = 0; j < 16; ++j) r[j] = 0.f;
    for (int kk = 0; kk < 64; ++kk) {
      float a = Sb[ri * 64 + kk];
#pragma unroll
      for (int j = 0; j < 16; ++j) r[j] += a * Sb[kk * 64 + jb + j];
    }
    __syncthreads();
#pragma unroll
    for (int j = 0; j < 16; ++j) Ab[ri * 64 + jb + j] = r[j];
    __syncthreads();
    for (int it = 0; it < 16; ++it) {
      int e = t + 256 * it;
      base[1 * 4096 + e] = (_Float16)Ab[e];
    }
  }
  // P3 = P2*P1 (write direct from regs), P4 = P2*P2
  {
    float r3[16], r4[16];
#pragma unroll
    for (int j = 0; j < 16; ++j) { r3[j] = 0.f; r4[j] = 0.f; }
    for (int kk = 0; kk < 64; ++kk) {
      float a = Ab[ri * 64 + kk];
#pragma unroll
      for (int j = 0; j < 16; ++j) {
        r3[j] += a * Sb[kk * 64 + jb + j];
        r4[j] += a * Ab[kk * 64 + jb + j];
      }
    }
#pragma unroll
    for (int j = 0; j < 16; ++j) {
      base[2 * 4096 + ri * 64 + jb + j] = (_Float16)r3[j];
      base[3 * 4096 + ri * 64 + jb + j] = (_Float16)r4[j];
    }
  }
}

// ============================================================================
// Kernel 2: fused pruning. Block = 256 thr (4 waves), 64 sites staged as f16
// in 64KB LDS (XOR-swizzled). Wave w does components m = w and w+4, both
// 32-site subtiles. Tree state in registers (packed half2), cross-lane
// D->B-operand relayout via v_permlane32_swap_b32.
// ============================================================================
struct Pk { half2v h[16]; };  // h[rt*8+p] packs (acc[rt][2p], acc[rt][2p+1])

__device__ __forceinline__ void swap32(unsigned& a, unsigned& b) {
#if __has_builtin(__builtin_amdgcn_permlane32_swap)
  uint2v r = __builtin_amdgcn_permlane32_swap(a, b, false, false);
  a = r.x; b = r.y;
#else
  unsigned pa = (unsigned)__shfl_xor((int)a, 32, 64);
  unsigned pb = (unsigned)__shfl_xor((int)b, 32, 64);
  bool hi = (threadIdx.x & 32) != 0;
  unsigned na = hi ? pb : a;
  unsigned nb = hi ? b : pa;
  a = na; b = nb;
#endif
}

__device__ __forceinline__ half8v bfrag_state(const Pk& s, int kt) {
  const int rt = kt >> 1, b = (kt & 1) * 4;
  unsigned a0 = __builtin_bit_cast(unsigned, s.h[rt * 8 + b + 0]);
  unsigned c0 = __builtin_bit_cast(unsigned, s.h[rt * 8 + b + 2]);
  unsigned a1 = __builtin_bit_cast(unsigned, s.h[rt * 8 + b + 1]);
  unsigned c1 = __builtin_bit_cast(unsigned, s.h[rt * 8 + b + 3]);
  swap32(a0, c0);
  swap32(a1, c1);
  union { half8v v; unsigned u[4]; } U;
  U.u[0] = a0; U.u[1] = a1; U.u[2] = c0; U.u[3] = c1;
  return U.v;
}

__device__ __forceinline__ void zero16(f32x16& a) {
#pragma unroll
  for (int i = 0; i < 16; ++i) a[i] = 0.f;
}

__device__ __forceinline__ Pk pack2(const f32x16 a[2]) {
  Pk o;
#pragma unroll
  for (int rt = 0; rt < 2; ++rt)
#pragma unroll
    for (int p = 0; p < 8; ++p) {
      half2v h;
      h.x = (_Float16)a[rt][2 * p];
      h.y = (_Float16)a[rt][2 * p + 1];
      o.h[rt * 8 + p] = h;
    }
  return o;
}

__device__ __forceinline__ void msg_leaf(const _Float16* __restrict__ Pv,
                                         const _Float16* __restrict__ xs,
                                         int leaf, int nst, int s31, int hb, int sw,
                                         f32x16 acc[2][2]) {
  half8v pf0[4], pf1[4];
#pragma unroll
  for (int kt = 0; kt < 4; ++kt) {
    pf0[kt] = *(const half8v*)(Pv + (s31 * 64 + kt * 16 + hb * 8));
    pf1[kt] = *(const half8v*)(Pv + ((32 + s31) * 64 + kt * 16 + hb * 8));
  }
#pragma unroll
  for (int st = 0; st < 2; ++st) {
    if (st >= nst) continue;
    f32x16 a0, a1;
    zero16(a0); zero16(a1);
#pragma unroll
    for (int kt = 0; kt < 4; ++kt) {
      half8v bf = *(const half8v*)(xs + (st * 32 + s31) * 512 +
                                   ((leaf * 64 + kt * 16 + hb * 8) ^ sw));
      a0 = __builtin_amdgcn_mfma_f32_32x32x16_f16(pf0[kt], bf, a0, 0, 0, 0);
      a1 = __builtin_amdgcn_mfma_f32_32x32x16_f16(pf1[kt], bf, a1, 0, 0, 0);
    }
    acc[st][0] = a0; acc[st][1] = a1;
  }
}

__device__ __forceinline__ void msg_state(const _Float16* __restrict__ Pv,
                                          const Pk src[2], int nst, int s31, int hb,
                                          f32x16 acc[2][2]) {
  half8v pf0[4], pf1[4];
#pragma unroll
  for (int kt = 0; kt < 4; ++kt) {
    pf0[kt] = *(const half8v*)(Pv + (s31 * 64 + kt * 16 + hb * 8));
    pf1[kt] = *(const half8v*)(Pv + ((32 + s31) * 64 + kt * 16 + hb * 8));
  }
#pragma unroll
  for (int st = 0; st < 2; ++st) {
    if (st >= nst) continue;
    f32x16 a0, a1;
    zero16(a0); zero16(a1);
#pragma unroll
    for (int kt = 0; kt < 4; ++kt) {
      half8v bf = bfrag_state(src[st], kt);
      a0 = __builtin_amdgcn_mfma_f32_32x32x16_f16(pf0[kt], bf, a0, 0, 0, 0);
      a1 = __builtin_amdgcn_mfma_f32_32x32x16_f16(pf1[kt], bf, a1, 0, 0, 0);
    }
    acc[st][0] = a0; acc[st][1] = a1;
  }
}

__device__ __forceinline__ void combine(const Pk mL[2], const f32x16 aR[2][2],
                                        int nst, Pk dst[2]) {
#pragma unroll
  for (int st = 0; st < 2; ++st) {
    if (st >= nst) continue;
    Pk pR = pack2(aR[st]);
#pragma unroll
    for (int i = 0; i < 16; ++i) dst[st].h[i] = mL[st].h[i] * pR.h[i];
  }
}

__global__ __launch_bounds__(256, 2) void tree_fwd(const float* __restrict__ X,
                                                   const _Float16* __restrict__ Pw,
                                                   float* __restrict__ out) {
  __shared__ __align__(16) _Float16 xs[64 * 512];  // 64 KiB, swizzled f16 X tile
  const int t = threadIdx.x;
  const int sb0 = blockIdx.x * 64;
  const int nsv = (NS - sb0) < 64 ? (NS - sb0) : 64;

  // ---- stage X (fp32 global, coalesced) -> f16 LDS, XOR-swizzle bits 3..5 ----
  for (int it = 0; it < 32; ++it) {
    int c4 = t + 256 * it;
    int e0 = c4 * 4;
    int site = e0 >> 9;
    int k = e0 & 511;
    float4 v = {0.f, 0.f, 0.f, 0.f};
    if (site < nsv) v = ((const float4*)X)[(size_t)(sb0 + site) * 128 + (k >> 2)];
    half4v h;
    h.x = (_Float16)v.x; h.y = (_Float16)v.y; h.z = (_Float16)v.z; h.w = (_Float16)v.w;
    *(half4v*)(xs + site * 512 + (k ^ ((site & 7) << 3))) = h;
  }
  __syncthreads();

  const int lane = t & 63, wav = t >> 6;
  const int s31 = lane & 31, hb = lane >> 5;
  const int sw = (s31 & 7) << 3;
  const int nst = (NS - sb0) >= 64 ? 2 : 1;

#pragma unroll 1
  for (int mp = 0; mp < 2; ++mp) {
    const int m = wav + 4 * mp;
    const _Float16* Pm = Pw + (size_t)m * 5 * 4096;
    Pk sA[2], sB[2], s12[2], s13[2], mL[2];
    f32x16 acc[2][2];

    // node 8 : leaves 0 (t=.05 -> v0), 1 (v1)
    msg_leaf(Pm + 0 * 4096, xs, 0, nst, s31, hb, sw, acc);
#pragma unroll
    for (int st = 0; st < 2; ++st) if (st < nst) mL[st] = pack2(acc[st]);
    msg_leaf(Pm + 1 * 4096, xs, 1, nst, s31, hb, sw, acc);
    combine(mL, acc, nst, sA);
    // node 9 : leaves 2 (v2), 3 (v3)
    msg_leaf(Pm + 2 * 4096, xs, 2, nst, s31, hb, sw, acc);
#pragma unroll
    for (int st = 0; st < 2; ++st) if (st < nst) mL[st] = pack2(acc[st]);
    msg_leaf(Pm + 3 * 4096, xs, 3, nst, s31, hb, sw, acc);
    combine(mL, acc, nst, sB);
    // node 12 : children node8 (e8 -> v0), node9 (e9 -> v1)
    msg_state(Pm + 0 * 4096, sA, nst, s31, hb, acc);
#pragma unroll
    for (int st = 0; st < 2; ++st) if (st < nst) mL[st] = pack2(acc[st]);
    msg_state(Pm + 1 * 4096, sB, nst, s31, hb, acc);
    combine(mL, acc, nst, s12);
    // node 10 : leaves 4 (v0), 5 (v1)   (reuse sA)
    msg_leaf(Pm + 0 * 4096, xs, 4, nst, s31, hb, sw, acc);
#pragma unroll
    for (int st = 0; st < 2; ++st) if (st < nst) mL[st] = pack2(acc[st]);
    msg_leaf(Pm + 1 * 4096, xs, 5, nst, s31, hb, sw, acc);
    combine(mL, acc, nst, sA);
    // node 11 : leaves 6 (v2), 7 (v3)   (reuse sB)
    msg_leaf(Pm + 2 * 4096, xs, 6, nst, s31, hb, sw, acc);
#pragma unroll
    for (int st = 0; st < 2; ++st) if (st < nst) mL[st] = pack2(acc[st]);
    msg_leaf(Pm + 3 * 4096, xs, 7, nst, s31, hb, sw, acc);
    combine(mL, acc, nst, sB);
    // node 13 : children node10 (e10 -> v2), node11 (e11 -> v3)
    msg_state(Pm + 2 * 4096, sA, nst, s31, hb, acc);
#pragma unroll
    for (int st = 0; st < 2; ++st) if (st < nst) mL[st] = pack2(acc[st]);
    msg_state(Pm + 3 * 4096, sB, nst, s31, hb, acc);
    combine(mL, acc, nst, s13);
    // root 14 : node12 via e12 (t=.05, pi-folded -> v4), node13 via e13 (v1)
    msg_state(Pm + 4 * 4096, s12, nst, s31, hb, acc);
#pragma unroll
    for (int st = 0; st < 2; ++st) if (st < nst) mL[st] = pack2(acc[st]);
    msg_state(Pm + 1 * 4096, s13, nst, s31, hb, acc);
#pragma unroll
    for (int st = 0; st < 2; ++st) {
      if (st >= nst) continue;
      float part = 0.f;
#pragma unroll
      for (int rt = 0; rt < 2; ++rt)
#pragma unroll
        for (int p = 0; p < 8; ++p) {
          part += (float)mL[st].h[rt * 8 + p].x * acc[st][rt][2 * p]
                + (float)mL[st].h[rt * 8 + p].y * acc[st][rt][2 * p + 1];
        }
      part += __shfl_xor(part, 32, 64);
      if (lane < 32) out[(size_t)(sb0 + st * 32 + s31) * 8 + m] = part;
    }
  }
}

extern "C" void kernel_launch(void* const* d_in, const int* in_sizes, int n_in,
                              void* d_out, int out_size, void* d_ws, size_t ws_size,
                              hipStream_t stream) {
  const float* X      = (const float*)d_in[0];
  const float* rates  = (const float*)d_in[1];
  const float* pi_inv = (const float*)d_in[2];
  _Float16* Pw = (_Float16*)d_ws;   // 8 * 5 * 4096 * 2B = 320 KiB

  prep_P<<<8, 256, 0, stream>>>(rates, pi_inv, Pw);
  tree_fwd<<<(NS + 63) / 64, 256, 0, stream>>>(X, Pw, (float*)d_out);
}

// Round 2
// 810.535 us; speedup vs baseline: 1.0930x; 1.0930x over previous
//
#include <hip/hip_runtime.h>

#define NS 100000

typedef _Float16 half8v __attribute__((ext_vector_type(8)));
typedef _Float16 half4v __attribute__((ext_vector_type(4)));
typedef _Float16 half2v __attribute__((ext_vector_type(2)));
typedef float    f32x16 __attribute__((ext_vector_type(16)));
typedef unsigned int uint2v __attribute__((ext_vector_type(2)));

// ============================================================================
// Kernel 1: build Q per component (fp32, LDS), expm via scaling+squaring
// Taylor (terms to k=8, ||A||1 <= 0.25), then P^{1,2,3,4} + pi-folded P1.
// 4x4 register-tiled fp32 matmuls; T maintained transposed so all LDS
// reads are float4. Store f16 row-major in d_ws: Pw[m][v][64][64].
// ============================================================================
__device__ __forceinline__ void mm64(const float* __restrict__ Lt,
                                     const float* __restrict__ Rn,
                                     int ro, int co, float r[16]) {
#pragma unroll 4
  for (int kk0 = 0; kk0 < 64; kk0 += 4) {
    float4 tv[4], av[4];
#pragma unroll
    for (int j = 0; j < 4; ++j) {
      tv[j] = *(const float4*)(Lt + (kk0 + j) * 64 + ro);
      av[j] = *(const float4*)(Rn + (kk0 + j) * 64 + co);
    }
#pragma unroll
    for (int j = 0; j < 4; ++j) {
      const float* tp = (const float*)&tv[j];
      const float* ap = (const float*)&av[j];
#pragma unroll
      for (int i = 0; i < 4; ++i)
#pragma unroll
        for (int c = 0; c < 4; ++c) r[i * 4 + c] += tp[i] * ap[c];
    }
  }
}

__global__ __launch_bounds__(256) void prep_P(const float* __restrict__ rates,
                                              const float* __restrict__ pi_inv,
                                              _Float16* __restrict__ Pw) {
  __shared__ __align__(16) float Ab[4096];
  __shared__ __align__(16) float Tt[4096];
  __shared__ __align__(16) float Sb[4096];
  __shared__ float pi_l[64];
  __shared__ float red[64];
  __shared__ float sc_sh[2];
  const int t = threadIdx.x;
  const int m = blockIdx.x;

  // ---- pi from inverse stereographic projection ----
  if (t < 63) { float y = pi_inv[m * 63 + t]; red[t] = y * y; }
  __syncthreads();
  if (t == 0) { double ns = 0.0; for (int i = 0; i < 63; ++i) ns += red[i]; sc_sh[0] = (float)ns; }
  __syncthreads();
  {
    float ns = sc_sh[0];
    if (t < 64) {
      float ps;
      if (t < 63) { float y = pi_inv[m * 63 + t]; ps = 2.f * y / (ns + 1.f); }
      else        { ps = (ns - 1.f) / (ns + 1.f); }
      pi_l[t] = ps * ps;
    }
  }
  __syncthreads();

  // ---- Q (off-diag) in Ab ----
  for (int it = 0; it < 16; ++it) {
    int e = t + 256 * it, i = e >> 6, j = e & 63;
    float v = 0.f;
    if (i != j) {
      int ii = i < j ? i : j, jj = i < j ? j : i;
      int tri = ii * 63 - (ii * (ii - 1)) / 2 + (jj - ii - 1);
      float r = rates[m * 2016 + tri];
      v = r * r * pi_l[j];
    }
    Ab[e] = v;
  }
  __syncthreads();
  // ---- diagonal + emut ----
  if (t < 64) {
    float s = 0.f;
    for (int j = 0; j < 64; ++j) s += Ab[t * 64 + j];
    Ab[t * 64 + t] = -s;
    red[t] = pi_l[t] * s;
  }
  __syncthreads();
  if (t == 0) { double em = 0.0; for (int i = 0; i < 64; ++i) em += red[i]; sc_sh[0] = (float)(0.05 / em); }
  __syncthreads();
  const float sc0 = sc_sh[0];
  // ---- 1-norm of (0.05/emut)*Q -> scaling exponent ----
  if (t < 64) {
    float s = 0.f;
    for (int i = 0; i < 64; ++i) s += fabsf(Ab[i * 64 + t]);
    red[t] = s * fabsf(sc0);
  }
  __syncthreads();
  if (t == 0) {
    float n1 = 0.f; for (int i = 0; i < 64; ++i) n1 = fmaxf(n1, red[i]);
    int sq = 0;
    while (n1 > 0.25f && sq < 24) { n1 *= 0.5f; ++sq; }
    sc_sh[0] = ldexpf(sc0, -sq);
    sc_sh[1] = (float)sq;
  }
  __syncthreads();
  const float scl = sc_sh[0];
  const int   sq  = (int)sc_sh[1];
  // ---- A = scaled Q (normal in Ab, transposed in Tt) ----
  for (int it = 0; it < 16; ++it) {
    int e = t + 256 * it, i = e >> 6, j = e & 63;
    float a = Ab[e] * scl;
    Ab[e] = a;
    Tt[j * 64 + i] = a;
  }
  __syncthreads();

  const int ro = (t >> 4) * 4, co = (t & 15) * 4;
  float ss[16];
#pragma unroll
  for (int i = 0; i < 16; ++i) ss[i] = 0.f;

  // ---- Taylor: T_k = T_{k-1} * A / k, S-sum tracked in registers ----
  for (int k = 2; k <= 8; ++k) {
    float r[16];
#pragma unroll
    for (int i = 0; i < 16; ++i) r[i] = 0.f;
    mm64(Tt, Ab, ro, co, r);
    __syncthreads();
    float inv = 1.f / (float)k;
#pragma unroll
    for (int i = 0; i < 16; ++i) { r[i] *= inv; ss[i] += r[i]; }
#pragma unroll
    for (int j = 0; j < 4; ++j) {
      float4 w = {r[0 * 4 + j], r[1 * 4 + j], r[2 * 4 + j], r[3 * 4 + j]};
      *(float4*)(Tt + (co + j) * 64 + ro) = w;
    }
    __syncthreads();
  }

  // ---- assemble S = I + A + sum, store normal (Sb) + transposed (Tt) ----
  float s[16];
#pragma unroll
  for (int i = 0; i < 4; ++i)
#pragma unroll
    for (int j = 0; j < 4; ++j)
      s[i * 4 + j] = ss[i * 4 + j] + Ab[(ro + i) * 64 + co + j] +
                     (((ro + i) == (co + j)) ? 1.f : 0.f);
  __syncthreads();   // everyone done reading Tt (taylor) / Ab
#pragma unroll
  for (int i = 0; i < 4; ++i) {
    float4 w = {s[i * 4 + 0], s[i * 4 + 1], s[i * 4 + 2], s[i * 4 + 3]};
    *(float4*)(Sb + (ro + i) * 64 + co) = w;
  }
#pragma unroll
  for (int j = 0; j < 4; ++j) {
    float4 w = {s[0 * 4 + j], s[1 * 4 + j], s[2 * 4 + j], s[3 * 4 + j]};
    *(float4*)(Tt + (co + j) * 64 + ro) = w;
  }
  __syncthreads();

  // ---- repeated squaring (usually sq == 0) ----
  for (int q = 0; q < sq; ++q) {
    float r[16];
#pragma unroll
    for (int i = 0; i < 16; ++i) r[i] = 0.f;
    mm64(Tt, Sb, ro, co, r);
    __syncthreads();
#pragma unroll
    for (int i = 0; i < 16; ++i) s[i] = r[i];
#pragma unroll
    for (int i = 0; i < 4; ++i) {
      float4 w = {s[i * 4 + 0], s[i * 4 + 1], s[i * 4 + 2], s[i * 4 + 3]};
      *(float4*)(Sb + (ro + i) * 64 + co) = w;
    }
#pragma unroll
    for (int j = 0; j < 4; ++j) {
      float4 w = {s[0 * 4 + j], s[1 * 4 + j], s[2 * 4 + j], s[3 * 4 + j]};
      *(float4*)(Tt + (co + j) * 64 + ro) = w;
    }
    __syncthreads();
  }

  _Float16* base = Pw + (size_t)m * 5 * 4096;
  // ---- P1 (v0) + pi-folded P1 (v4) from register tile ----
#pragma unroll
  for (int i = 0; i < 4; ++i) {
    half4v h1, h4;
#pragma unroll
    for (int j = 0; j < 4; ++j) {
      float v = s[i * 4 + j];
      h1[j] = (_Float16)v;
      h4[j] = (_Float16)(pi_l[ro + i] * v);
    }
    *(half4v*)(base + (ro + i) * 64 + co)            = h1;
    *(half4v*)(base + 4 * 4096 + (ro + i) * 64 + co) = h4;
  }
  // ---- P2 = S*S ----
  float p2[16];
#pragma unroll
  for (int i = 0; i < 16; ++i) p2[i] = 0.f;
  mm64(Tt, Sb, ro, co, p2);
  __syncthreads();   // done reading Tt(S^T); Ab free
#pragma unroll
  for (int i = 0; i < 4; ++i) {
    float4 w = {p2[i * 4 + 0], p2[i * 4 + 1], p2[i * 4 + 2], p2[i * 4 + 3]};
    *(float4*)(Ab + (ro + i) * 64 + co) = w;
    half4v h;
#pragma unroll
    for (int j = 0; j < 4; ++j) h[j] = (_Float16)p2[i * 4 + j];
    *(half4v*)(base + 1 * 4096 + (ro + i) * 64 + co) = h;
  }
#pragma unroll
  for (int j = 0; j < 4; ++j) {
    float4 w = {p2[0 * 4 + j], p2[1 * 4 + j], p2[2 * 4 + j], p2[3 * 4 + j]};
    *(float4*)(Tt + (co + j) * 64 + ro) = w;
  }
  __syncthreads();
  // ---- P3 = P2*P1, P4 = P2*P2 (fused: share P2^T loads) ----
  {
    float r3[16], r4[16];
#pragma unroll
    for (int i = 0; i < 16; ++i) { r3[i] = 0.f; r4[i] = 0.f; }
#pragma unroll 2
    for (int kk0 = 0; kk0 < 64; kk0 += 4) {
      float4 tv[4], a3[4], a4[4];
#pragma unroll
      for (int j = 0; j < 4; ++j) {
        tv[j] = *(const float4*)(Tt + (kk0 + j) * 64 + ro);
        a3[j] = *(const float4*)(Sb + (kk0 + j) * 64 + co);
        a4[j] = *(const float4*)(Ab + (kk0 + j) * 64 + co);
      }
#pragma unroll
      for (int j = 0; j < 4; ++j) {
        const float* tp = (const float*)&tv[j];
        const float* p3 = (const float*)&a3[j];
        const float* p4 = (const float*)&a4[j];
#pragma unroll
        for (int i = 0; i < 4; ++i)
#pragma unroll
          for (int c = 0; c < 4; ++c) {
            r3[i * 4 + c] += tp[i] * p3[c];
            r4[i * 4 + c] += tp[i] * p4[c];
          }
      }
    }
#pragma unroll
    for (int i = 0; i < 4; ++i) {
      half4v h3, h4;
#pragma unroll
      for (int j = 0; j < 4; ++j) {
        h3[j] = (_Float16)r3[i * 4 + j];
        h4[j] = (_Float16)r4[i * 4 + j];
      }
      *(half4v*)(base + 2 * 4096 + (ro + i) * 64 + co) = h3;
      *(half4v*)(base + 3 * 4096 + (ro + i) * 64 + co) = h4;
    }
  }
}

// ============================================================================
// Kernel 2: fused pruning. Block = 256 thr (4 waves), 64 sites of X staged as
// f16 in 64KB LDS (XOR-swizzled). Wave w does components m = w and w+4.
// Messages pack f32 acc -> f16 immediately (keeps liveness ~190 regs, no
// spill). Cross-lane D->B relayout via v_permlane32_swap_b32.
// ============================================================================
struct Pk { half2v h[16]; };  // h[rt*8+p] packs (acc[rt][2p], acc[rt][2p+1])
struct PF { half8v f0[4], f1[4]; };

__device__ __forceinline__ void swap32(unsigned& a, unsigned& b) {
#if __has_builtin(__builtin_amdgcn_permlane32_swap)
  uint2v r = __builtin_amdgcn_permlane32_swap(a, b, false, false);
  a = r.x; b = r.y;
#else
  unsigned pa = (unsigned)__shfl_xor((int)a, 32, 64);
  unsigned pb = (unsigned)__shfl_xor((int)b, 32, 64);
  bool hi = (threadIdx.x & 32) != 0;
  unsigned na = hi ? pb : a;
  unsigned nb = hi ? b : pa;
  a = na; b = nb;
#endif
}

__device__ __forceinline__ half8v bfrag_state(const Pk& s, int kt) {
  const int rt = kt >> 1, b = (kt & 1) * 4;
  unsigned a0 = __builtin_bit_cast(unsigned, s.h[rt * 8 + b + 0]);
  unsigned c0 = __builtin_bit_cast(unsigned, s.h[rt * 8 + b + 2]);
  unsigned a1 = __builtin_bit_cast(unsigned, s.h[rt * 8 + b + 1]);
  unsigned c1 = __builtin_bit_cast(unsigned, s.h[rt * 8 + b + 3]);
  swap32(a0, c0);
  swap32(a1, c1);
  union { half8v v; unsigned u[4]; } U;
  U.u[0] = a0; U.u[1] = a1; U.u[2] = c0; U.u[3] = c1;
  return U.v;
}

__device__ __forceinline__ void zero16(f32x16& a) {
#pragma unroll
  for (int i = 0; i < 16; ++i) a[i] = 0.f;
}

__device__ __forceinline__ Pk pack_acc(const f32x16& a0, const f32x16& a1) {
  Pk o;
#pragma unroll
  for (int p = 0; p < 8; ++p) {
    half2v h0, h1;
    h0.x = (_Float16)a0[2 * p]; h0.y = (_Float16)a0[2 * p + 1];
    h1.x = (_Float16)a1[2 * p]; h1.y = (_Float16)a1[2 * p + 1];
    o.h[p] = h0; o.h[8 + p] = h1;
  }
  return o;
}

__device__ __forceinline__ PF load_pf(const _Float16* __restrict__ Pv,
                                      int s31, int hb) {
  PF pf;
#pragma unroll
  for (int kt = 0; kt < 4; ++kt) {
    pf.f0[kt] = *(const half8v*)(Pv + (s31 * 64 + kt * 16 + hb * 8));
    pf.f1[kt] = *(const half8v*)(Pv + ((32 + s31) * 64 + kt * 16 + hb * 8));
  }
  return pf;
}

// leaf message: out[st] = pack( P * X[:, leaf, :]^T ) for each 32-site subtile
__device__ __forceinline__ void msg_leaf_pk(const _Float16* __restrict__ Pv,
                                            const _Float16* __restrict__ xs,
                                            int leaf, int nst, int s31, int hb,
                                            int sw, Pk out[2]) {
  PF pf = load_pf(Pv, s31, hb);
#pragma unroll
  for (int st = 0; st < 2; ++st) {
    if (st >= nst) continue;
    f32x16 a0, a1;
    zero16(a0); zero16(a1);
#pragma unroll
    for (int kt = 0; kt < 4; ++kt) {
      half8v bf = *(const half8v*)(xs + (st * 32 + s31) * 512 +
                                   ((leaf * 64 + kt * 16 + hb * 8) ^ sw));
      a0 = __builtin_amdgcn_mfma_f32_32x32x16_f16(pf.f0[kt], bf, a0, 0, 0, 0);
      a1 = __builtin_amdgcn_mfma_f32_32x32x16_f16(pf.f1[kt], bf, a1, 0, 0, 0);
    }
    out[st] = pack_acc(a0, a1);
  }
}

// internal message: out[st] = pack( P * state[st] )
__device__ __forceinline__ void msg_state_pk(const _Float16* __restrict__ Pv,
                                             const Pk src[2], int nst, int s31,
                                             int hb, Pk out[2]) {
  PF pf = load_pf(Pv, s31, hb);
#pragma unroll
  for (int st = 0; st < 2; ++st) {
    if (st >= nst) continue;
    f32x16 a0, a1;
    zero16(a0); zero16(a1);
#pragma unroll
    for (int kt = 0; kt < 4; ++kt) {
      half8v bf = bfrag_state(src[st], kt);
      a0 = __builtin_amdgcn_mfma_f32_32x32x16_f16(pf.f0[kt], bf, a0, 0, 0, 0);
      a1 = __builtin_amdgcn_mfma_f32_32x32x16_f16(pf.f1[kt], bf, a1, 0, 0, 0);
    }
    out[st] = pack_acc(a0, a1);
  }
}

__device__ __forceinline__ void mulpk(Pk dst[2], const Pk a[2], const Pk b[2],
                                      int nst) {
#pragma unroll
  for (int st = 0; st < 2; ++st) {
    if (st >= nst) continue;
#pragma unroll
    for (int i = 0; i < 16; ++i) dst[st].h[i] = a[st].h[i] * b[st].h[i];
  }
}

__global__ __launch_bounds__(256, 2) void tree_fwd(const float* __restrict__ X,
                                                   const _Float16* __restrict__ Pw,
                                                   float* __restrict__ out) {
  __shared__ __align__(16) _Float16 xs[64 * 512];  // 64 KiB, swizzled f16 X tile
  const int t = threadIdx.x;
  const int sb0 = blockIdx.x * 64;
  const int nsv = (NS - sb0) < 64 ? (NS - sb0) : 64;

  // ---- stage X (fp32 global, coalesced) -> f16 LDS, XOR-swizzle bits 3..5 ----
  for (int it = 0; it < 32; ++it) {
    int c4 = t + 256 * it;
    int e0 = c4 * 4;
    int site = e0 >> 9;
    int k = e0 & 511;
    float4 v = {0.f, 0.f, 0.f, 0.f};
    if (site < nsv) v = ((const float4*)X)[(size_t)(sb0 + site) * 128 + (k >> 2)];
    half4v h;
    h.x = (_Float16)v.x; h.y = (_Float16)v.y; h.z = (_Float16)v.z; h.w = (_Float16)v.w;
    *(half4v*)(xs + site * 512 + (k ^ ((site & 7) << 3))) = h;
  }
  __syncthreads();

  const int lane = t & 63, wav = t >> 6;
  const int s31 = lane & 31, hb = lane >> 5;
  const int sw = (s31 & 7) << 3;
  const int nst = (NS - sb0) >= 64 ? 2 : 1;

#pragma unroll 1
  for (int mp = 0; mp < 2; ++mp) {
    const int m = wav + 4 * mp;
    const _Float16* Pm = Pw + (size_t)m * 5 * 4096;
    Pk mA[2], mB[2], sA[2], sB[2], s12[2], s13[2];

    // node 8 : leaves 0 (v0), 1 (v1)
    msg_leaf_pk(Pm + 0 * 4096, xs, 0, nst, s31, hb, sw, mA);
    msg_leaf_pk(Pm + 1 * 4096, xs, 1, nst, s31, hb, sw, mB);
    mulpk(sA, mA, mB, nst);
    // node 9 : leaves 2 (v2), 3 (v3)
    msg_leaf_pk(Pm + 2 * 4096, xs, 2, nst, s31, hb, sw, mA);
    msg_leaf_pk(Pm + 3 * 4096, xs, 3, nst, s31, hb, sw, mB);
    mulpk(sB, mA, mB, nst);
    // node 12 : node8 (v0), node9 (v1)
    msg_state_pk(Pm + 0 * 4096, sA, nst, s31, hb, mA);
    msg_state_pk(Pm + 1 * 4096, sB, nst, s31, hb, mB);
    mulpk(s12, mA, mB, nst);
    // node 10 : leaves 4 (v0), 5 (v1)
    msg_leaf_pk(Pm + 0 * 4096, xs, 4, nst, s31, hb, sw, mA);
    msg_leaf_pk(Pm + 1 * 4096, xs, 5, nst, s31, hb, sw, mB);
    mulpk(sA, mA, mB, nst);
    // node 11 : leaves 6 (v2), 7 (v3)
    msg_leaf_pk(Pm + 2 * 4096, xs, 6, nst, s31, hb, sw, mA);
    msg_leaf_pk(Pm + 3 * 4096, xs, 7, nst, s31, hb, sw, mB);
    mulpk(sB, mA, mB, nst);
    // node 13 : node10 (v2), node11 (v3)
    msg_state_pk(Pm + 2 * 4096, sA, nst, s31, hb, mA);
    msg_state_pk(Pm + 3 * 4096, sB, nst, s31, hb, mB);
    mulpk(s13, mA, mB, nst);
    // root 14 : node12 via v4 (pi-folded P1), node13 via v1; dot + reduce
    msg_state_pk(Pm + 4 * 4096, s12, nst, s31, hb, mA);
    {
      PF pf = load_pf(Pm + 1 * 4096, s31, hb);
#pragma unroll
      for (int st = 0; st < 2; ++st) {
        if (st >= nst) continue;
        f32x16 a0, a1;
        zero16(a0); zero16(a1);
#pragma unroll
        for (int kt = 0; kt < 4; ++kt) {
          half8v bf = bfrag_state(s13[st], kt);
          a0 = __builtin_amdgcn_mfma_f32_32x32x16_f16(pf.f0[kt], bf, a0, 0, 0, 0);
          a1 = __builtin_amdgcn_mfma_f32_32x32x16_f16(pf.f1[kt], bf, a1, 0, 0, 0);
        }
        float part = 0.f;
#pragma unroll
        for (int p = 0; p < 8; ++p) {
          part += (float)mA[st].h[p].x     * a0[2 * p]
                + (float)mA[st].h[p].y     * a0[2 * p + 1]
                + (float)mA[st].h[8 + p].x * a1[2 * p]
                + (float)mA[st].h[8 + p].y * a1[2 * p + 1];
        }
        part += __shfl_xor(part, 32, 64);
        if (lane < 32) out[(size_t)(sb0 + st * 32 + s31) * 8 + m] = part;
      }
    }
  }
}

extern "C" void kernel_launch(void* const* d_in, const int* in_sizes, int n_in,
                              void* d_out, int out_size, void* d_ws, size_t ws_size,
                              hipStream_t stream) {
  const float* X      = (const float*)d_in[0];
  const float* rates  = (const float*)d_in[1];
  const float* pi_inv = (const float*)d_in[2];
  _Float16* Pw = (_Float16*)d_ws;   // 8 * 5 * 4096 * 2B = 320 KiB

  prep_P<<<8, 256, 0, stream>>>(rates, pi_inv, Pw);
  tree_fwd<<<(NS + 63) / 64, 256, 0, stream>>>(X, Pw, (float*)d_out);
}

// Round 4
// 523.891 us; speedup vs baseline: 1.6911x; 1.5471x over previous
//
#include <hip/hip_runtime.h>

#define NS 100000

typedef _Float16 half8v __attribute__((ext_vector_type(8)));
typedef _Float16 half4v __attribute__((ext_vector_type(4)));
typedef _Float16 half2v __attribute__((ext_vector_type(2)));
typedef float    f32x16 __attribute__((ext_vector_type(16)));
typedef unsigned int uint2v __attribute__((ext_vector_type(2)));

// ============================================================================
// Kernel 1: build Q per component (fp32, LDS), expm via scaling+squaring
// Taylor (terms to k=8, ||A||1 <= 0.25), then P^{1,2,3,4} + pi-folded P1.
// 4x4 register-tiled fp32 matmuls; wave-shuffle reductions for the scalar
// sums. Store f16: Pw[m][v][64][64].
// ============================================================================
__device__ __forceinline__ float wave_sum64(float v) {
#pragma unroll
  for (int off = 32; off > 0; off >>= 1) v += __shfl_xor(v, off, 64);
  return v;
}
__device__ __forceinline__ float wave_max64(float v) {
#pragma unroll
  for (int off = 32; off > 0; off >>= 1) v = fmaxf(v, __shfl_xor(v, off, 64));
  return v;
}

__device__ __forceinline__ void mm64(const float* __restrict__ Lt,
                                     const float* __restrict__ Rn,
                                     int ro, int co, float r[16]) {
#pragma unroll 4
  for (int kk0 = 0; kk0 < 64; kk0 += 4) {
    float4 tv[4], av[4];
#pragma unroll
    for (int j = 0; j < 4; ++j) {
      tv[j] = *(const float4*)(Lt + (kk0 + j) * 64 + ro);
      av[j] = *(const float4*)(Rn + (kk0 + j) * 64 + co);
    }
#pragma unroll
    for (int j = 0; j < 4; ++j) {
      const float* tp = (const float*)&tv[j];
      const float* ap = (const float*)&av[j];
#pragma unroll
      for (int i = 0; i < 4; ++i)
#pragma unroll
        for (int c = 0; c < 4; ++c) r[i * 4 + c] += tp[i] * ap[c];
    }
  }
}

__global__ __launch_bounds__(256) void prep_P(const float* __restrict__ rates,
                                              const float* __restrict__ pi_inv,
                                              _Float16* __restrict__ Pw) {
  __shared__ __align__(16) float Ab[4096];
  __shared__ __align__(16) float Tt[4096];
  __shared__ __align__(16) float Sb[4096];
  __shared__ float pi_l[64];
  __shared__ float sc_sh[2];
  const int t = threadIdx.x;
  const int m = blockIdx.x;

  // ---- pi from inverse stereographic projection (wave 0 only) ----
  if (t < 64) {
    float y = (t < 63) ? pi_inv[m * 63 + t] : 0.f;
    float ns = wave_sum64(y * y);
    float ps = (t < 63) ? (2.f * y / (ns + 1.f)) : ((ns - 1.f) / (ns + 1.f));
    pi_l[t] = ps * ps;
  }
  __syncthreads();

  // ---- Q (off-diag) in Ab ----
  for (int it = 0; it < 16; ++it) {
    int e = t + 256 * it, i = e >> 6, j = e & 63;
    float v = 0.f;
    if (i != j) {
      int ii = i < j ? i : j, jj = i < j ? j : i;
      int tri = ii * 63 - (ii * (ii - 1)) / 2 + (jj - ii - 1);
      float r = rates[m * 2016 + tri];
      v = r * r * pi_l[j];
    }
    Ab[e] = v;
  }
  __syncthreads();
  // ---- diagonal + emut (row sums, rotated index -> no bank conflict) ----
  if (t < 64) {
    float s = 0.f;
    for (int j = 0; j < 64; ++j) s += Ab[t * 64 + ((j + t) & 63)];
    Ab[t * 64 + t] = -s;
    float em = wave_sum64(pi_l[t] * s);
    if (t == 0) sc_sh[0] = 0.05f / em;
  }
  __syncthreads();
  const float sc0 = sc_sh[0];
  // ---- 1-norm of sc0*Q -> scaling exponent ----
  if (t < 64) {
    float s = 0.f;
    for (int i = 0; i < 64; ++i) s += fabsf(Ab[i * 64 + t]);
    float n1 = wave_max64(s * fabsf(sc0));
    if (t == 0) {
      int sq = 0;
      while (n1 > 0.25f && sq < 24) { n1 *= 0.5f; ++sq; }
      sc_sh[0] = ldexpf(sc0, -sq);
      sc_sh[1] = (float)sq;
    }
  }
  __syncthreads();
  const float scl = sc_sh[0];
  const int   sq  = (int)sc_sh[1];
  // ---- A = scaled Q (normal in Ab, transposed in Tt) ----
  for (int it = 0; it < 16; ++it) {
    int e = t + 256 * it, i = e >> 6, j = e & 63;
    float a = Ab[e] * scl;
    Ab[e] = a;
    Tt[j * 64 + i] = a;
  }
  __syncthreads();

  const int ro = (t >> 4) * 4, co = (t & 15) * 4;
  float ss[16];
#pragma unroll
  for (int i = 0; i < 16; ++i) ss[i] = 0.f;

  // ---- Taylor: T_k = T_{k-1} * A / k, S-sum tracked in registers ----
  for (int k = 2; k <= 8; ++k) {
    float r[16];
#pragma unroll
    for (int i = 0; i < 16; ++i) r[i] = 0.f;
    mm64(Tt, Ab, ro, co, r);
    __syncthreads();
    float inv = 1.f / (float)k;
#pragma unroll
    for (int i = 0; i < 16; ++i) { r[i] *= inv; ss[i] += r[i]; }
#pragma unroll
    for (int j = 0; j < 4; ++j) {
      float4 w = {r[0 * 4 + j], r[1 * 4 + j], r[2 * 4 + j], r[3 * 4 + j]};
      *(float4*)(Tt + (co + j) * 64 + ro) = w;
    }
    __syncthreads();
  }

  // ---- assemble S = I + A + sum, store normal (Sb) + transposed (Tt) ----
  float s[16];
#pragma unroll
  for (int i = 0; i < 4; ++i)
#pragma unroll
    for (int j = 0; j < 4; ++j)
      s[i * 4 + j] = ss[i * 4 + j] + Ab[(ro + i) * 64 + co + j] +
                     (((ro + i) == (co + j)) ? 1.f : 0.f);
  __syncthreads();
#pragma unroll
  for (int i = 0; i < 4; ++i) {
    float4 w = {s[i * 4 + 0], s[i * 4 + 1], s[i * 4 + 2], s[i * 4 + 3]};
    *(float4*)(Sb + (ro + i) * 64 + co) = w;
  }
#pragma unroll
  for (int j = 0; j < 4; ++j) {
    float4 w = {s[0 * 4 + j], s[1 * 4 + j], s[2 * 4 + j], s[3 * 4 + j]};
    *(float4*)(Tt + (co + j) * 64 + ro) = w;
  }
  __syncthreads();

  // ---- repeated squaring (usually sq == 0) ----
  for (int q = 0; q < sq; ++q) {
    float r[16];
#pragma unroll
    for (int i = 0; i < 16; ++i) r[i] = 0.f;
    mm64(Tt, Sb, ro, co, r);
    __syncthreads();
#pragma unroll
    for (int i = 0; i < 16; ++i) s[i] = r[i];
#pragma unroll
    for (int i = 0; i < 4; ++i) {
      float4 w = {s[i * 4 + 0], s[i * 4 + 1], s[i * 4 + 2], s[i * 4 + 3]};
      *(float4*)(Sb + (ro + i) * 64 + co) = w;
    }
#pragma unroll
    for (int j = 0; j < 4; ++j) {
      float4 w = {s[0 * 4 + j], s[1 * 4 + j], s[2 * 4 + j], s[3 * 4 + j]};
      *(float4*)(Tt + (co + j) * 64 + ro) = w;
    }
    __syncthreads();
  }

  _Float16* base = Pw + (size_t)m * 5 * 4096;
  // ---- P1 (v0) + pi-folded P1 (v4) from register tile ----
#pragma unroll
  for (int i = 0; i < 4; ++i) {
    half4v h1, h4;
#pragma unroll
    for (int j = 0; j < 4; ++j) {
      float v = s[i * 4 + j];
      h1[j] = (_Float16)v;
      h4[j] = (_Float16)(pi_l[ro + i] * v);
    }
    *(half4v*)(base + (ro + i) * 64 + co)            = h1;
    *(half4v*)(base + 4 * 4096 + (ro + i) * 64 + co) = h4;
  }
  // ---- P2 = S*S ----
  float p2[16];
#pragma unroll
  for (int i = 0; i < 16; ++i) p2[i] = 0.f;
  mm64(Tt, Sb, ro, co, p2);
  __syncthreads();
#pragma unroll
  for (int i = 0; i < 4; ++i) {
    float4 w = {p2[i * 4 + 0], p2[i * 4 + 1], p2[i * 4 + 2], p2[i * 4 + 3]};
    *(float4*)(Ab + (ro + i) * 64 + co) = w;
    half4v h;
#pragma unroll
    for (int j = 0; j < 4; ++j) h[j] = (_Float16)p2[i * 4 + j];
    *(half4v*)(base + 1 * 4096 + (ro + i) * 64 + co) = h;
  }
#pragma unroll
  for (int j = 0; j < 4; ++j) {
    float4 w = {p2[0 * 4 + j], p2[1 * 4 + j], p2[2 * 4 + j], p2[3 * 4 + j]};
    *(float4*)(Tt + (co + j) * 64 + ro) = w;
  }
  __syncthreads();
  // ---- P3 = P2*P1, P4 = P2*P2 (fused: share P2^T loads) ----
  {
    float r3[16], r4[16];
#pragma unroll
    for (int i = 0; i < 16; ++i) { r3[i] = 0.f; r4[i] = 0.f; }
#pragma unroll 2
    for (int kk0 = 0; kk0 < 64; kk0 += 4) {
      float4 tv[4], a3[4], a4[4];
#pragma unroll
      for (int j = 0; j < 4; ++j) {
        tv[j] = *(const float4*)(Tt + (kk0 + j) * 64 + ro);
        a3[j] = *(const float4*)(Sb + (kk0 + j) * 64 + co);
        a4[j] = *(const float4*)(Ab + (kk0 + j) * 64 + co);
      }
#pragma unroll
      for (int j = 0; j < 4; ++j) {
        const float* tp = (const float*)&tv[j];
        const float* p3 = (const float*)&a3[j];
        const float* p4 = (const float*)&a4[j];
#pragma unroll
        for (int i = 0; i < 4; ++i)
#pragma unroll
          for (int c = 0; c < 4; ++c) {
            r3[i * 4 + c] += tp[i] * p3[c];
            r4[i * 4 + c] += tp[i] * p4[c];
          }
      }
    }
#pragma unroll
    for (int i = 0; i < 4; ++i) {
      half4v h3, h4;
#pragma unroll
      for (int j = 0; j < 4; ++j) {
        h3[j] = (_Float16)r3[i * 4 + j];
        h4[j] = (_Float16)r4[i * 4 + j];
      }
      *(half4v*)(base + 2 * 4096 + (ro + i) * 64 + co) = h3;
      *(half4v*)(base + 3 * 4096 + (ro + i) * 64 + co) = h4;
    }
  }
}

// ============================================================================
// Kernel 2: fused pruning. Block = 256 thr (4 waves), 32 sites of X staged as
// f16 in 32KB LDS (XOR-swizzled). Wave w handles the SAME 32-site subtile for
// components m = w and w+4 (sequential) -> single-subtile state: peak liveness
// ~4 Pk (64 VGPR) + pf(32) + acc(32), no scratch spill. 100000 = 3125*32, no
// tail. Cross-lane D->B relayout via v_permlane32_swap_b32.
// ============================================================================
struct Pk { half2v h[16]; };  // h[rt*8+p] packs (acc_rt[2p], acc_rt[2p+1])
struct PF { half8v f0[4], f1[4]; };

__device__ __forceinline__ void swap32(unsigned& a, unsigned& b) {
#if __has_builtin(__builtin_amdgcn_permlane32_swap)
  uint2v r = __builtin_amdgcn_permlane32_swap(a, b, false, false);
  a = r.x; b = r.y;
#else
  unsigned pa = (unsigned)__shfl_xor((int)a, 32, 64);
  unsigned pb = (unsigned)__shfl_xor((int)b, 32, 64);
  bool hi = (threadIdx.x & 32) != 0;
  unsigned na = hi ? pb : a;
  unsigned nb = hi ? b : pa;
  a = na; b = nb;
#endif
}

__device__ __forceinline__ half8v bfrag_state(const Pk& s, int kt) {
  const int rt = kt >> 1, b = (kt & 1) * 4;
  unsigned a0 = __builtin_bit_cast(unsigned, s.h[rt * 8 + b + 0]);
  unsigned c0 = __builtin_bit_cast(unsigned, s.h[rt * 8 + b + 2]);
  unsigned a1 = __builtin_bit_cast(unsigned, s.h[rt * 8 + b + 1]);
  unsigned c1 = __builtin_bit_cast(unsigned, s.h[rt * 8 + b + 3]);
  swap32(a0, c0);
  swap32(a1, c1);
  union { half8v v; unsigned u[4]; } U;
  U.u[0] = a0; U.u[1] = a1; U.u[2] = c0; U.u[3] = c1;
  return U.v;
}

__device__ __forceinline__ void zero16(f32x16& a) {
#pragma unroll
  for (int i = 0; i < 16; ++i) a[i] = 0.f;
}

__device__ __forceinline__ Pk pack_acc(const f32x16& a0, const f32x16& a1) {
  Pk o;
#pragma unroll
  for (int p = 0; p < 8; ++p) {
    o.h[p]     = __builtin_bit_cast(half2v,
                   __builtin_amdgcn_cvt_pkrtz(a0[2 * p], a0[2 * p + 1]));
    o.h[8 + p] = __builtin_bit_cast(half2v,
                   __builtin_amdgcn_cvt_pkrtz(a1[2 * p], a1[2 * p + 1]));
  }
  return o;
}

__device__ __forceinline__ PF load_pf(const _Float16* __restrict__ Pv,
                                      int s31, int hb) {
  PF pf;
#pragma unroll
  for (int kt = 0; kt < 4; ++kt) {
    pf.f0[kt] = *(const half8v*)(Pv + (s31 * 64 + kt * 16 + hb * 8));
    pf.f1[kt] = *(const half8v*)(Pv + ((32 + s31) * 64 + kt * 16 + hb * 8));
  }
  return pf;
}

__device__ __forceinline__ Pk msg_leaf_pk(const _Float16* __restrict__ Pv,
                                          const _Float16* __restrict__ xs,
                                          int leaf, int s31, int hb, int sw) {
  PF pf = load_pf(Pv, s31, hb);
  f32x16 a0, a1;
  zero16(a0); zero16(a1);
#pragma unroll
  for (int kt = 0; kt < 4; ++kt) {
    half8v bf = *(const half8v*)(xs + s31 * 512 +
                                 ((leaf * 64 + kt * 16 + hb * 8) ^ sw));
    a0 = __builtin_amdgcn_mfma_f32_32x32x16_f16(pf.f0[kt], bf, a0, 0, 0, 0);
    a1 = __builtin_amdgcn_mfma_f32_32x32x16_f16(pf.f1[kt], bf, a1, 0, 0, 0);
  }
  return pack_acc(a0, a1);
}

__device__ __forceinline__ Pk msg_state_pk(const _Float16* __restrict__ Pv,
                                           const Pk& src, int s31, int hb) {
  PF pf = load_pf(Pv, s31, hb);
  f32x16 a0, a1;
  zero16(a0); zero16(a1);
#pragma unroll
  for (int kt = 0; kt < 4; ++kt) {
    half8v bf = bfrag_state(src, kt);
    a0 = __builtin_amdgcn_mfma_f32_32x32x16_f16(pf.f0[kt], bf, a0, 0, 0, 0);
    a1 = __builtin_amdgcn_mfma_f32_32x32x16_f16(pf.f1[kt], bf, a1, 0, 0, 0);
  }
  return pack_acc(a0, a1);
}

__device__ __forceinline__ Pk mulpk(const Pk& a, const Pk& b) {
  Pk o;
#pragma unroll
  for (int i = 0; i < 16; ++i) o.h[i] = a.h[i] * b.h[i];
  return o;
}

__global__ __launch_bounds__(256, 2) void tree_fwd(const float* __restrict__ X,
                                                   const _Float16* __restrict__ Pw,
                                                   float* __restrict__ out) {
  __shared__ __align__(16) _Float16 xs[32 * 512];  // 32 KiB swizzled f16 X tile
  const int t = threadIdx.x;
  const int sb0 = blockIdx.x * 32;

  // ---- stage X (fp32 global, coalesced) -> f16 LDS, XOR-swizzle bits 3..5 ----
  for (int it = 0; it < 16; ++it) {
    int e0 = (t + 256 * it) * 4;
    int site = e0 >> 9;
    int k = e0 & 511;
    float4 v = ((const float4*)X)[(size_t)(sb0 + site) * 128 + (k >> 2)];
    half4v h;
    h.x = (_Float16)v.x; h.y = (_Float16)v.y; h.z = (_Float16)v.z; h.w = (_Float16)v.w;
    *(half4v*)(xs + site * 512 + (k ^ ((site & 7) << 3))) = h;
  }
  __syncthreads();

  const int lane = t & 63, wav = t >> 6;
  const int s31 = lane & 31, hb = lane >> 5;
  const int sw = (s31 & 7) << 3;

#pragma unroll 1
  for (int mp = 0; mp < 2; ++mp) {
    const int m = wav + 4 * mp;
    const _Float16* Pm = Pw + (size_t)m * 5 * 4096;

    // node 8 : leaves 0 (v0), 1 (v1);  node 9 : leaves 2 (v2), 3 (v3)
    Pk sA = mulpk(msg_leaf_pk(Pm + 0 * 4096, xs, 0, s31, hb, sw),
                  msg_leaf_pk(Pm + 1 * 4096, xs, 1, s31, hb, sw));
    Pk sB = mulpk(msg_leaf_pk(Pm + 2 * 4096, xs, 2, s31, hb, sw),
                  msg_leaf_pk(Pm + 3 * 4096, xs, 3, s31, hb, sw));
    // node 12 : node8 (v0), node9 (v1)
    Pk s12 = mulpk(msg_state_pk(Pm + 0 * 4096, sA, s31, hb),
                   msg_state_pk(Pm + 1 * 4096, sB, s31, hb));
    // node 10 : leaves 4 (v0), 5 (v1);  node 11 : leaves 6 (v2), 7 (v3)
    sA = mulpk(msg_leaf_pk(Pm + 0 * 4096, xs, 4, s31, hb, sw),
               msg_leaf_pk(Pm + 1 * 4096, xs, 5, s31, hb, sw));
    sB = mulpk(msg_leaf_pk(Pm + 2 * 4096, xs, 6, s31, hb, sw),
               msg_leaf_pk(Pm + 3 * 4096, xs, 7, s31, hb, sw));
    // node 13 : node10 (v2), node11 (v3)
    Pk s13 = mulpk(msg_state_pk(Pm + 2 * 4096, sA, s31, hb),
                   msg_state_pk(Pm + 3 * 4096, sB, s31, hb));
    // root 14 : node12 via v4 (pi-folded P1), node13 via v1; dot + reduce
    Pk mL = msg_state_pk(Pm + 4 * 4096, s12, s31, hb);
    {
      PF pf = load_pf(Pm + 1 * 4096, s31, hb);
      f32x16 a0, a1;
      zero16(a0); zero16(a1);
#pragma unroll
      for (int kt = 0; kt < 4; ++kt) {
        half8v bf = bfrag_state(s13, kt);
        a0 = __builtin_amdgcn_mfma_f32_32x32x16_f16(pf.f0[kt], bf, a0, 0, 0, 0);
        a1 = __builtin_amdgcn_mfma_f32_32x32x16_f16(pf.f1[kt], bf, a1, 0, 0, 0);
      }
      float part = 0.f;
#pragma unroll
      for (int p = 0; p < 8; ++p) {
        part += (float)mL.h[p].x     * a0[2 * p]
              + (float)mL.h[p].y     * a0[2 * p + 1]
              + (float)mL.h[8 + p].x * a1[2 * p]
              + (float)mL.h[8 + p].y * a1[2 * p + 1];
      }
      part += __shfl_xor(part, 32, 64);
      if (lane < 32) out[(size_t)(sb0 + s31) * 8 + m] = part;
    }
  }
}

extern "C" void kernel_launch(void* const* d_in, const int* in_sizes, int n_in,
                              void* d_out, int out_size, void* d_ws, size_t ws_size,
                              hipStream_t stream) {
  const float* X      = (const float*)d_in[0];
  const float* rates  = (const float*)d_in[1];
  const float* pi_inv = (const float*)d_in[2];
  _Float16* Pw = (_Float16*)d_ws;   // 8 * 5 * 4096 * 2B = 320 KiB

  prep_P<<<8, 256, 0, stream>>>(rates, pi_inv, Pw);
  tree_fwd<<<NS / 32, 256, 0, stream>>>(X, Pw, (float*)d_out);
}